// Round 1
// baseline (301.565 us; speedup 1.0000x reference)
//
#include <hip/hip_runtime.h>
#include <hip/hip_bf16.h>
#include <cstdint>
#include <cstddef>

#define NUM_NODES 500000
#define DIM 128
#define BATCH 131072

typedef __attribute__((ext_vector_type(8))) short short8;
typedef __attribute__((ext_vector_type(4))) short short4_t;
typedef __attribute__((ext_vector_type(4))) float f32x4;

static __device__ __forceinline__ short f2bf(float f) {
    unsigned u = __builtin_bit_cast(unsigned, f);
    u += 0x7fffu + ((u >> 16) & 1u);   // round-to-nearest-even
    return (short)(u >> 16);
}

// ---------------------------------------------------------------- init ----
__global__ void k_init(int* __restrict__ mask,
                       const float* __restrict__ Wih,
                       const float* __restrict__ Whh,
                       short* __restrict__ WbIH,
                       short* __restrict__ WbHH,
                       int do_mask) {
    int i = blockIdx.x * blockDim.x + threadIdx.x;
    if (do_mask && i < NUM_NODES) mask[i] = 0;
    if (i < 3 * DIM * DIM) {
        WbIH[i] = f2bf(Wih[i]);
        WbHH[i] = f2bf(Whh[i]);
    }
}

__global__ void k_scatter(int* __restrict__ mask, const int* __restrict__ idx) {
    int i = blockIdx.x * blockDim.x + threadIdx.x;
    if (i < BATCH) mask[idx[i]] = 1;
}

// ---------------------------------------------------------------- copy ----
// one thread per (row, 4-float chunk); 32 chunks/row, both planes
__global__ void k_copy(const float* __restrict__ hidden,
                       const float* __restrict__ variance,
                       const int* __restrict__ mask,   // may be null -> copy all
                       float* __restrict__ out0,
                       float* __restrict__ out1) {
    int gid = blockIdx.x * blockDim.x + threadIdx.x;
    int row = gid >> 5;
    int c4  = gid & 31;
    if (row >= NUM_NODES) return;
    if (mask && mask[row]) return;                 // updated row: gru kernel writes it
    size_t off = (size_t)row * DIM + c4 * 4;
    *(f32x4*)(out0 + off) = *(const f32x4*)(hidden + off);
    *(f32x4*)(out1 + off) = *(const f32x4*)(variance + off);
}

// ----------------------------------------------------------------- gru ----
// block: 512 threads = 8 waves, handles 32 batch rows.
// wave w owns output dims d = 16w..16w+15 for all three gate thirds
// (N-tiles w, w+8, w+16) -> gate combine is lane-local in MFMA C layout.
__global__ void __launch_bounds__(512)
k_gru(const float* __restrict__ hidden,
      const float* __restrict__ variance,
      const int*   __restrict__ idx,
      const float* __restrict__ xg,       // new_repr
      const short* __restrict__ WbIH,     // [384][128] bf16 bits
      const short* __restrict__ WbHH,
      const float* __restrict__ b_ih,
      const float* __restrict__ b_hh,
      float* __restrict__ out0,
      float* __restrict__ out1) {
    __shared__ short Xb[32][136];   // bf16 x tile, padded stride (16B aligned rows)
    __shared__ short Hb[32][136];   // bf16 h tile
    __shared__ float Hf[32][132];   // f32 h tile for epilogue
    __shared__ int   nodeS[32];

    const int t  = threadIdx.x;
    const int rb = blockIdx.x * 32;

    // ---- stage x (f32->bf16) and gathered h (f32->bf16 + f32) ----
    for (int j = t; j < 1024; j += 512) {          // 1024 float4 chunks
        int row = j >> 5, c4 = j & 31;
        int node = idx[rb + row];
        f32x4 xv = *(const f32x4*)(xg + (size_t)(rb + row) * DIM + c4 * 4);
        f32x4 hv = *(const f32x4*)(hidden + (size_t)node * DIM + c4 * 4);
        short4_t xs, hs;
        xs.x = f2bf(xv.x); xs.y = f2bf(xv.y); xs.z = f2bf(xv.z); xs.w = f2bf(xv.w);
        hs.x = f2bf(hv.x); hs.y = f2bf(hv.y); hs.z = f2bf(hv.z); hs.w = f2bf(hv.w);
        *(short4_t*)&Xb[row][c4 * 4] = xs;
        *(short4_t*)&Hb[row][c4 * 4] = hs;
        *(f32x4*)&Hf[row][c4 * 4]    = hv;
    }
    if (t < 32) nodeS[t] = idx[rb + t];
    __syncthreads();

    const int w = t >> 6;        // wave id 0..7
    const int l = t & 63;
    const int c = l & 15;
    const int g = l >> 4;

    f32x4 acc[2][3][2] = {};     // [m-tile][gate third][gemm: 0=x@Wih 1=h@Whh]

    #pragma unroll
    for (int ks = 0; ks < 4; ++ks) {
        const int k0 = ks * 32 + g * 8;
        short8 a[2][2];
        a[0][0] = *(const short8*)&Xb[c][k0];
        a[1][0] = *(const short8*)&Xb[16 + c][k0];
        a[0][1] = *(const short8*)&Hb[c][k0];
        a[1][1] = *(const short8*)&Hb[16 + c][k0];
        #pragma unroll
        for (int th = 0; th < 3; ++th) {
            const int o = w * 16 + th * 128 + c;            // gate output row of W
            const short8 bi = *(const short8*)(WbIH + (size_t)o * DIM + k0);
            const short8 bh = *(const short8*)(WbHH + (size_t)o * DIM + k0);
            #pragma unroll
            for (int mt = 0; mt < 2; ++mt) {
                acc[mt][th][0] = __builtin_amdgcn_mfma_f32_16x16x32_bf16(a[mt][0], bi, acc[mt][th][0], 0, 0, 0);
                acc[mt][th][1] = __builtin_amdgcn_mfma_f32_16x16x32_bf16(a[mt][1], bh, acc[mt][th][1], 0, 0, 0);
            }
        }
    }

    // ---- epilogue: lane holds (m = mt*16 + g*4 + r, d = w*16 + c) ----
    const int d = w * 16 + c;
    const float bs_r = b_ih[d]       + b_hh[d];
    const float bs_z = b_ih[d + 128] + b_hh[d + 128];
    const float bi_n = b_ih[d + 256];
    const float bh_n = b_hh[d + 256];

    #pragma unroll
    for (int mt = 0; mt < 2; ++mt) {
        #pragma unroll
        for (int r = 0; r < 4; ++r) {
            const int m = mt * 16 + g * 4 + r;
            float s_r  = acc[mt][0][0][r] + acc[mt][0][1][r] + bs_r;
            float s_z  = acc[mt][1][0][r] + acc[mt][1][1][r] + bs_z;
            float gi_n = acc[mt][2][0][r] + bi_n;
            float gh_n = acc[mt][2][1][r] + bh_n;
            float rg = 1.f / (1.f + __expf(-s_r));
            float zg = 1.f / (1.f + __expf(-s_z));
            float n  = tanhf(gi_n + rg * gh_n);
            float h  = Hf[m][d];
            float hn = (1.f - zg) * n + zg * h;
            float dl = hn - h;
            int node = nodeS[m];
            size_t off = (size_t)node * DIM + d;
            float var = 0.9f * variance[off] + 0.1f * dl * dl;
            out0[off] = hn;
            out1[off] = var;
        }
    }
}

// -------------------------------------------------------------- launch ----
extern "C" void kernel_launch(void* const* d_in, const int* in_sizes, int n_in,
                              void* d_out, int out_size, void* d_ws, size_t ws_size,
                              hipStream_t stream) {
    const float* hidden   = (const float*)d_in[0];
    const float* variance = (const float*)d_in[1];
    const int*   idx      = (const int*)d_in[2];
    const float* x        = (const float*)d_in[3];
    const float* Wih      = (const float*)d_in[4];
    const float* Whh      = (const float*)d_in[5];
    const float* bih      = (const float*)d_in[6];
    const float* bhh      = (const float*)d_in[7];
    float* out0 = (float*)d_out;
    float* out1 = out0 + (size_t)NUM_NODES * DIM;

    const size_t maskBytes = (size_t)NUM_NODES * 4;
    const size_t wBytes    = (size_t)3 * DIM * DIM * 2;      // per matrix
    const bool   have_mask = ws_size >= maskBytes + 2 * wBytes;

    int*   mask = have_mask ? (int*)d_ws : nullptr;
    short* WbIH = have_mask ? (short*)((char*)d_ws + maskBytes) : (short*)d_ws;
    short* WbHH = WbIH + 3 * DIM * DIM;

    k_init<<<(NUM_NODES + 255) / 256, 256, 0, stream>>>(mask ? mask : (int*)d_ws,
                                                        Wih, Whh, WbIH, WbHH,
                                                        have_mask ? 1 : 0);
    if (have_mask)
        k_scatter<<<BATCH / 256, 256, 0, stream>>>(mask, idx);

    // copy first (copy-all fallback is then overwritten by gru below)
    k_copy<<<((size_t)NUM_NODES * 32 + 255) / 256, 256, 0, stream>>>(
        hidden, variance, mask, out0, out1);

    k_gru<<<BATCH / 32, 512, 0, stream>>>(hidden, variance, idx, x,
                                          WbIH, WbHH, bih, bhh, out0, out1);
}